// Round 16
// baseline (165.221 us; speedup 1.0000x reference)
//
#include <hip/hip_runtime.h>
#include <hip/hip_bf16.h>

#define TB 256   // T (sequence length)
#define CC 64    // C (embed)
#define HH 64    // H (head size)

typedef __attribute__((ext_vector_type(8))) short short8;   // 8 bf16 (4 VGPRs)
typedef __attribute__((ext_vector_type(4))) float f32x4;    // MFMA C/D frag

#define MFMA16(a, b, c) __builtin_amdgcn_mfma_f32_16x16x32_bf16((a), (b), (c), 0, 0, 0)

// Packed f32->bf16 pair via HIP intrinsic (lowers to v_cvt_pk_bf16_f32) — proven R12.
__device__ __forceinline__ unsigned cvt2(float lo, float hi) {
    union { __hip_bfloat162 h2; unsigned u; } cv;
    cv.h2 = __float22bfloat162_rn(make_float2(lo, hi));
    return cv.u;
}

union S8U { short8 s8; unsigned u32[4]; unsigned long long u64[2]; };

__device__ __forceinline__ short8 pack8(f32x4 a, f32x4 b) {
    S8U r;
    r.u32[0] = cvt2(a[0], a[1]);
    r.u32[1] = cvt2(a[2], a[3]);
    r.u32[2] = cvt2(b[0], b[1]);
    r.u32[3] = cvt2(b[2], b[3]);
    return r.s8;
}

__device__ __forceinline__ unsigned long long pack4(f32x4 a) {
    S8U r;
    r.u32[0] = cvt2(a[0], a[1]);
    r.u32[1] = cvt2(a[2], a[3]);
    return r.u64[0];
}

// Pre-kernel: W -> MFMA-ready bf16 fragments (proven R4). Layout byte-identical to wb frags.
__global__ __launch_bounds__(512, 1)
void pack_w(const float* __restrict__ Wq, const float* __restrict__ Wk,
            const float* __restrict__ Wv, short8* __restrict__ wf) {
    const int tid  = threadIdx.x;
    const int lane = tid & 63;
    const int lr   = lane & 15;
    const int lg   = lane >> 4;
    const int idx  = tid >> 6;        // 0..7
    const int t    = idx >> 1;
    const int kk   = idx & 1;
    const float* Ws[3] = { Wq, Wk, Wv };
#pragma unroll
    for (int m = 0; m < 3; ++m) {
        const f32x4* p4 = (const f32x4*)(Ws[m] + (16 * t + lr) * CC + kk * 32 + lg * 8);
        wf[((m * 4 + t) * 2 + kk) * 64 + lane] = pack8(p4[0], p4[1]);
    }
}

// R14 shell (proven 65.9us) at 640 threads / 10 waves for 20 waves/CU (5/SIMD):
//  waves 0-5: strip pairs (w, 11-w) -> 7 tile-pairs each
//  waves 6-9: single strips 12..15 -> 7,7,8,8 tile-pairs (straggler 9->8)
// Singles set sA=sB, ntA=0: Phase A/B unchanged (redundant identical recompute —
// all defs UNGUARDED, consumption guarded by ntA; the R6-proven-safe shape).
template<bool WSF>
__global__ __launch_bounds__(640, 5)
void attn_fused(const float* __restrict__ x, const float* __restrict__ Wq,
                const float* __restrict__ Wk, const float* __restrict__ Wv,
                const short8* __restrict__ wf, float* __restrict__ out)
{
    // 64 KiB shared, phase-aliased: Phase B/C: kf(32K)+vq(32K); epilogue: fp32 stage[256][64]
    __shared__ __align__(16) char smem[65536];
    short8* kf_lds = (short8*)smem;                                   // [16][2][4][16]
    unsigned long long* vq_lds = (unsigned long long*)(smem + 32768); // [4][64][16]
    float* stage = (float*)smem;

    const int b    = blockIdx.x;
    const int tid  = threadIdx.x;
    const int wave = tid >> 6;        // 0..9
    const int lane = tid & 63;
    const int lr   = lane & 15;
    const int lg   = lane >> 4;
    const int xsw  = (lr & 7) << 1;   // vq swizzle (even -> preserves b128 pairing)

    const bool dual = (wave < 6);
    const int sB  = dual ? 11 - wave : wave + 6;   // heavy strip
    const int sA  = dual ? wave      : sB;         // singles: duplicate own strip (benign)
    const int ntA = dual ? wave + 1  : 0;          // A-consumption disabled for singles
    const int ntB = sB + 1;

    const float kexp = 0.125f * 1.44269504088896f;   // scale * log2(e), folded into Q

    // all-ones bf16 B-tile fragment (0x3F80 = bf16 1.0)
    const short8 ones = { (short)0x3F80, (short)0x3F80, (short)0x3F80, (short)0x3F80,
                          (short)0x3F80, (short)0x3F80, (short)0x3F80, (short)0x3F80 };

    // ---------- Phase A: x fragments for both strips ----------
    short8 xa[2][2];
#pragma unroll
    for (int sp = 0; sp < 2; ++sp) {
        const int s = sp ? sB : sA;
        const float* xr = x + ((size_t)b * TB + s * 16 + lr) * CC;
#pragma unroll
        for (int kk = 0; kk < 2; ++kk) {
            const f32x4* p4 = (const f32x4*)(xr + kk * 32 + lg * 8);
            xa[sp][kk] = pack8(p4[0], p4[1]);
        }
    }

    // ---------- Phase B: q^T,k^T = W@x^T (lane=pos); v = x@W^T (lane=h) — proven R4 ----------
    short8 qfA[2], qfB[2];
    const float* Ws[3] = { Wq, Wk, Wv };
#pragma unroll
    for (int m = 0; m < 3; ++m) {
        short8 wb[4][2];
        if constexpr (WSF) {
#pragma unroll
            for (int t = 0; t < 4; ++t)
#pragma unroll
                for (int kk = 0; kk < 2; ++kk)
                    wb[t][kk] = wf[((m * 4 + t) * 2 + kk) * 64 + lane];
        } else {
#pragma unroll
            for (int t = 0; t < 4; ++t)
#pragma unroll
                for (int kk = 0; kk < 2; ++kk) {
                    const f32x4* p4 = (const f32x4*)(Ws[m] + (16 * t + lr) * CC + kk * 32 + lg * 8);
                    wb[t][kk] = pack8(p4[0], p4[1]);
                }
        }
#pragma unroll
        for (int sp = 0; sp < 2; ++sp) {
            const int s = sp ? sB : sA;
            f32x4 acc[4];
#pragma unroll
            for (int t = 0; t < 4; ++t) acc[t] = (f32x4){0.f, 0.f, 0.f, 0.f};
#pragma unroll
            for (int kk = 0; kk < 2; ++kk)
#pragma unroll
                for (int t = 0; t < 4; ++t)
                    acc[t] = (m < 2) ? MFMA16(wb[t][kk], xa[sp][kk], acc[t])   // W in A slot -> transposed D
                                     : MFMA16(xa[sp][kk], wb[t][kk], acc[t]);  // x in A slot -> standard D

            if (m == 0) {
                // fold kexp into Q before bf16 pack (saves a mul per P elem in Phase C)
#pragma unroll
                for (int t = 0; t < 4; ++t)
#pragma unroll
                    for (int e = 0; e < 4; ++e) acc[t][e] *= kexp;
#pragma unroll
                for (int kk = 0; kk < 2; ++kk) {
                    short8 q = pack8(acc[2 * kk], acc[2 * kk + 1]);
                    if (sp) qfB[kk] = q; else qfA[kk] = q;
                }
            } else if (m == 1) {
#pragma unroll
                for (int kk = 0; kk < 2; ++kk)
                    kf_lds[((s * 2 + kk) * 4 + lg) * 16 + lr] = pack8(acc[2 * kk], acc[2 * kk + 1]);
            } else {
#pragma unroll
                for (int t = 0; t < 4; ++t)
                    vq_lds[(lg * 64 + 16 * t + lr) * 16 + (s ^ xsw)] = pack4(acc[t]);
            }
        }
    }
    __syncthreads();

    // ---------- Phase C: streaming causal attention; loads hoisted & shared (R11/R12) ----------
    f32x4 oA[4], oB[4];
#pragma unroll
    for (int t = 0; t < 4; ++t) {
        oA[t] = (f32x4){0.f, 0.f, 0.f, 0.f};
        oB[t] = (f32x4){0.f, 0.f, 0.f, 0.f};
    }
    f32x4 o4A = (f32x4){0.f, 0.f, 0.f, 0.f};   // row-sum accumulators (denominator)
    f32x4 o4B = (f32x4){0.f, 0.f, 0.f, 0.f};

#pragma unroll
    for (int kt = 0; kt < 8; ++kt) {
        const int j0 = 2 * kt, j1 = 2 * kt + 1;

        // ---- UNGUARDED shared loads (always in-bounds: kf has 16 tiles, vb slots even<=14) ----
        const short8 kf0a = kf_lds[((j0 * 2 + 0) * 4 + lg) * 16 + lr];
        const short8 kf0b = kf_lds[((j0 * 2 + 1) * 4 + lg) * 16 + lr];
        const short8 kf1a = kf_lds[((j1 * 2 + 0) * 4 + lg) * 16 + lr];
        const short8 kf1b = kf_lds[((j1 * 2 + 1) * 4 + lg) * 16 + lr];
        const short8 vb0 = *(const short8*)&vq_lds[(lg * 64 +  0 + lr) * 16 + (j0 ^ xsw)];
        const short8 vb1 = *(const short8*)&vq_lds[(lg * 64 + 16 + lr) * 16 + (j0 ^ xsw)];
        const short8 vb2 = *(const short8*)&vq_lds[(lg * 64 + 32 + lr) * 16 + (j0 ^ xsw)];
        const short8 vb3 = *(const short8*)&vq_lds[(lg * 64 + 48 + lr) * 16 + (j0 ^ xsw)];

        // ---- strip A tile-pair kt (never runs for singles: ntA=0) ----
        if (2 * kt < ntA) {
            f32x4 p0 = (f32x4){0.f, 0.f, 0.f, 0.f};
            f32x4 p1 = (f32x4){0.f, 0.f, 0.f, 0.f};
            p0 = MFMA16(kf0a, qfA[0], p0);
            p0 = MFMA16(kf0b, qfA[1], p0);
            const bool h1 = (j1 < ntA);
            if (h1) {
                p1 = MFMA16(kf1a, qfA[0], p1);
                p1 = MFMA16(kf1b, qfA[1], p1);
            }
#pragma unroll
            for (int e = 0; e < 4; ++e) p0[e] = __builtin_amdgcn_exp2f(p0[e]);
            if (j0 == sA) {
#pragma unroll
                for (int e = 0; e < 4; ++e) p0[e] = (4 * lg + e > lr) ? 0.f : p0[e];
            }
            if (h1) {
#pragma unroll
                for (int e = 0; e < 4; ++e) p1[e] = __builtin_amdgcn_exp2f(p1[e]);
                if (j1 == sA) {
#pragma unroll
                    for (int e = 0; e < 4; ++e) p1[e] = (4 * lg + e > lr) ? 0.f : p1[e];
                }
            }
            short8 pa = pack8(p0, p1);
            oA[0] = MFMA16(pa, vb0, oA[0]);
            oA[1] = MFMA16(pa, vb1, oA[1]);
            oA[2] = MFMA16(pa, vb2, oA[2]);
            oA[3] = MFMA16(pa, vb3, oA[3]);
            o4A   = MFMA16(pa, ones, o4A);     // denominator: row-sum of the SAME bf16 P
        }

        // ---- strip B tile-pair kt ----
        if (2 * kt < ntB) {
            f32x4 p0 = (f32x4){0.f, 0.f, 0.f, 0.f};
            f32x4 p1 = (f32x4){0.f, 0.f, 0.f, 0.f};
            p0 = MFMA16(kf0a, qfB[0], p0);
            p0 = MFMA16(kf0b, qfB[1], p0);
            const bool h1 = (j1 < ntB);
            if (h1) {
                p1 = MFMA16(kf1a, qfB[0], p1);
                p1 = MFMA16(kf1b, qfB[1], p1);
            }
#pragma unroll
            for (int e = 0; e < 4; ++e) p0[e] = __builtin_amdgcn_exp2f(p0[e]);
            if (j0 == sB) {
#pragma unroll
                for (int e = 0; e < 4; ++e) p0[e] = (4 * lg + e > lr) ? 0.f : p0[e];
            }
            if (h1) {
#pragma unroll
                for (int e = 0; e < 4; ++e) p1[e] = __builtin_amdgcn_exp2f(p1[e]);
                if (j1 == sB) {
#pragma unroll
                    for (int e = 0; e < 4; ++e) p1[e] = (4 * lg + e > lr) ? 0.f : p1[e];
                }
            }
            short8 pa = pack8(p0, p1);
            oB[0] = MFMA16(pa, vb0, oB[0]);
            oB[1] = MFMA16(pa, vb1, oB[1]);
            oB[2] = MFMA16(pa, vb2, oB[2]);
            oB[3] = MFMA16(pa, vb3, oB[3]);
            o4B   = MFMA16(pa, ones, o4B);
        }
    }

    // ---------- Epilogue: LDS restage -> coalesced dwordx4 stores (store-side skip for singles) ----------
    __syncthreads();
#pragma unroll
    for (int sp = 0; sp < 2; ++sp) {
        if (sp == 0 && ntA == 0) continue;           // singles own only sB
        const int s = sp ? sB : sA;
        const f32x4 o4 = sp ? o4B : o4A;
        float dn[4];
#pragma unroll
        for (int reg = 0; reg < 4; ++reg) dn[reg] = __builtin_amdgcn_rcpf(o4[reg]);
#pragma unroll
        for (int t = 0; t < 4; ++t)
#pragma unroll
            for (int reg = 0; reg < 4; ++reg) {
                const int row = 4 * lg + reg;                    // query row within strip
                const int col = (16 * t + lr) ^ (lg << 4);       // XOR key = row>>2 = lg
                const f32x4 o = sp ? oB[t] : oA[t];
                stage[(s * 16 + row) * 64 + col] = o[reg] * dn[reg];
            }
    }
    // own-wave data only: compiler inserts the lgkmcnt wait for the ds_write->ds_read dep
#pragma unroll
    for (int sp = 0; sp < 2; ++sp) {
        if (sp == 0 && ntA == 0) continue;
        const int s = sp ? sB : sA;
#pragma unroll
        for (int i = 0; i < 4; ++i) {
            const int row = 4 * i + lg;
            const int col = (4 * lr) ^ (i << 4);                 // XOR key = row>>2 = i
            f32x4 vv = *(const f32x4*)&stage[(s * 16 + row) * 64 + col];
            *(f32x4*)&out[((size_t)b * TB + 16 * s + row) * HH + 4 * lr] = vv;
        }
    }
}

extern "C" void kernel_launch(void* const* d_in, const int* in_sizes, int n_in,
                              void* d_out, int out_size, void* d_ws, size_t ws_size,
                              hipStream_t stream) {
    const float* x  = (const float*)d_in[0];
    const float* Wq = (const float*)d_in[1];
    const float* Wk = (const float*)d_in[2];
    const float* Wv = (const float*)d_in[3];
    float* out = (float*)d_out;
    const int Bn = in_sizes[0] / (TB * CC);   // 2048
    if (ws_size >= 3 * 4 * 2 * 64 * sizeof(short8)) {
        short8* wf = (short8*)d_ws;
        pack_w<<<1, 512, 0, stream>>>(Wq, Wk, Wv, wf);
        attn_fused<true><<<Bn, 640, 0, stream>>>(x, Wq, Wk, Wv, wf, out);
    } else {
        attn_fused<false><<<Bn, 640, 0, stream>>>(x, Wq, Wk, Wv, nullptr, out);
    }
}

// Round 17
// 113.749 us; speedup vs baseline: 1.4525x; 1.4525x over previous
//
#include <hip/hip_runtime.h>
#include <hip/hip_bf16.h>

#define TB 256   // T (sequence length)
#define CC 64    // C (embed)
#define HH 64    // H (head size)

typedef __attribute__((ext_vector_type(8))) short short8;   // 8 bf16 (4 VGPRs)
typedef __attribute__((ext_vector_type(4))) float f32x4;    // MFMA C/D frag

#define MFMA16(a, b, c) __builtin_amdgcn_mfma_f32_16x16x32_bf16((a), (b), (c), 0, 0, 0)

// Packed f32->bf16 pair via HIP intrinsic (lowers to v_cvt_pk_bf16_f32) — proven R12.
__device__ __forceinline__ unsigned cvt2(float lo, float hi) {
    union { __hip_bfloat162 h2; unsigned u; } cv;
    cv.h2 = __float22bfloat162_rn(make_float2(lo, hi));
    return cv.u;
}

union S8U { short8 s8; unsigned u32[4]; unsigned long long u64[2]; };

__device__ __forceinline__ short8 pack8(f32x4 a, f32x4 b) {
    S8U r;
    r.u32[0] = cvt2(a[0], a[1]);
    r.u32[1] = cvt2(a[2], a[3]);
    r.u32[2] = cvt2(b[0], b[1]);
    r.u32[3] = cvt2(b[2], b[3]);
    return r.s8;
}

__device__ __forceinline__ unsigned long long pack4(f32x4 a) {
    S8U r;
    r.u32[0] = cvt2(a[0], a[1]);
    r.u32[1] = cvt2(a[2], a[3]);
    return r.u64[0];
}

// Pre-kernel: W -> MFMA-ready bf16 fragments (proven R4). Layout byte-identical to wb frags.
__global__ __launch_bounds__(512, 1)
void pack_w(const float* __restrict__ Wq, const float* __restrict__ Wk,
            const float* __restrict__ Wv, short8* __restrict__ wf) {
    const int tid  = threadIdx.x;
    const int lane = tid & 63;
    const int lr   = lane & 15;
    const int lg   = lane >> 4;
    const int idx  = tid >> 6;        // 0..7
    const int t    = idx >> 1;
    const int kk   = idx & 1;
    const float* Ws[3] = { Wq, Wk, Wv };
#pragma unroll
    for (int m = 0; m < 3; ++m) {
        const f32x4* p4 = (const f32x4*)(Ws[m] + (16 * t + lr) * CC + kk * 32 + lg * 8);
        wf[((m * 4 + t) * 2 + kk) * 64 + lane] = pack8(p4[0], p4[1]);
    }
}

// R14 kernel (proven 65.9us) processing TWO batches per block (grid halved):
// halves ramp/drain tail rounds, amortizes per-block W-frag setup, and lets batch
// n+1's independent global x-loads issue under batch n's Phase C / epilogue.
// Per-batch body is verbatim R14; one extra end-of-batch barrier protects the
// stage <-> kf/vq LDS alias across batches. Block shape pinned at 512/LB(512,4)
// (1024- and 640-thread variants miscompile: R5/R13/R15).
template<bool WSF>
__global__ __launch_bounds__(512, 4)
void attn_fused(const float* __restrict__ x, const float* __restrict__ Wq,
                const float* __restrict__ Wk, const float* __restrict__ Wv,
                const short8* __restrict__ wf, float* __restrict__ out)
{
    // 64 KiB shared, phase-aliased: Phase B/C: kf(32K)+vq(32K); epilogue: fp32 stage[256][64]
    __shared__ __align__(16) char smem[65536];
    short8* kf_lds = (short8*)smem;                                   // [16][2][4][16]
    unsigned long long* vq_lds = (unsigned long long*)(smem + 32768); // [4][64][16]
    float* stage = (float*)smem;

    const int tid  = threadIdx.x;
    const int wave = tid >> 6;
    const int lane = tid & 63;
    const int lr   = lane & 15;
    const int lg   = lane >> 4;
    const int xsw  = (lr & 7) << 1;   // vq swizzle (even -> preserves b128 pairing)

    const int sA = wave;              // light strip (ntA <= 8)
    const int sB = 15 - wave;         // heavy strip (ntB >= 9)
    const int ntA = sA + 1;
    const int ntB = sB + 1;

    const float kexp = 0.125f * 1.44269504088896f;   // scale * log2(e), folded into Q

    // all-ones bf16 B-tile fragment (0x3F80 = bf16 1.0)
    const short8 ones = { (short)0x3F80, (short)0x3F80, (short)0x3F80, (short)0x3F80,
                          (short)0x3F80, (short)0x3F80, (short)0x3F80, (short)0x3F80 };

#pragma unroll
    for (int bb = 0; bb < 2; ++bb) {
        const int b = blockIdx.x * 2 + bb;

        // ---------- Phase A: x fragments for both strips ----------
        short8 xa[2][2];
#pragma unroll
        for (int sp = 0; sp < 2; ++sp) {
            const int s = sp ? sB : sA;
            const float* xr = x + ((size_t)b * TB + s * 16 + lr) * CC;
#pragma unroll
            for (int kk = 0; kk < 2; ++kk) {
                const f32x4* p4 = (const f32x4*)(xr + kk * 32 + lg * 8);
                xa[sp][kk] = pack8(p4[0], p4[1]);
            }
        }

        // ---------- Phase B: q^T,k^T = W@x^T (lane=pos); v = x@W^T (lane=h) — proven R4 ----------
        short8 qfA[2], qfB[2];
        const float* Ws[3] = { Wq, Wk, Wv };
#pragma unroll
        for (int m = 0; m < 3; ++m) {
            short8 wb[4][2];
            if constexpr (WSF) {
#pragma unroll
                for (int t = 0; t < 4; ++t)
#pragma unroll
                    for (int kk = 0; kk < 2; ++kk)
                        wb[t][kk] = wf[((m * 4 + t) * 2 + kk) * 64 + lane];
            } else {
#pragma unroll
                for (int t = 0; t < 4; ++t)
#pragma unroll
                    for (int kk = 0; kk < 2; ++kk) {
                        const f32x4* p4 = (const f32x4*)(Ws[m] + (16 * t + lr) * CC + kk * 32 + lg * 8);
                        wb[t][kk] = pack8(p4[0], p4[1]);
                    }
            }
#pragma unroll
            for (int sp = 0; sp < 2; ++sp) {
                const int s = sp ? sB : sA;
                f32x4 acc[4];
#pragma unroll
                for (int t = 0; t < 4; ++t) acc[t] = (f32x4){0.f, 0.f, 0.f, 0.f};
#pragma unroll
                for (int kk = 0; kk < 2; ++kk)
#pragma unroll
                    for (int t = 0; t < 4; ++t)
                        acc[t] = (m < 2) ? MFMA16(wb[t][kk], xa[sp][kk], acc[t])   // W in A slot -> transposed D
                                         : MFMA16(xa[sp][kk], wb[t][kk], acc[t]);  // x in A slot -> standard D

                if (m == 0) {
                    // fold kexp into Q before bf16 pack (saves a mul per P elem in Phase C)
#pragma unroll
                    for (int t = 0; t < 4; ++t)
#pragma unroll
                        for (int e = 0; e < 4; ++e) acc[t][e] *= kexp;
#pragma unroll
                    for (int kk = 0; kk < 2; ++kk) {
                        short8 q = pack8(acc[2 * kk], acc[2 * kk + 1]);
                        if (sp) qfB[kk] = q; else qfA[kk] = q;
                    }
                } else if (m == 1) {
#pragma unroll
                    for (int kk = 0; kk < 2; ++kk)
                        kf_lds[((s * 2 + kk) * 4 + lg) * 16 + lr] = pack8(acc[2 * kk], acc[2 * kk + 1]);
                } else {
#pragma unroll
                    for (int t = 0; t < 4; ++t)
                        vq_lds[(lg * 64 + 16 * t + lr) * 16 + (s ^ xsw)] = pack4(acc[t]);
                }
            }
        }
        __syncthreads();

        // ---------- Phase C: streaming causal attention; loads hoisted & shared (R11/R12) ----------
        f32x4 oA[4], oB[4];
#pragma unroll
        for (int t = 0; t < 4; ++t) {
            oA[t] = (f32x4){0.f, 0.f, 0.f, 0.f};
            oB[t] = (f32x4){0.f, 0.f, 0.f, 0.f};
        }
        f32x4 o4A = (f32x4){0.f, 0.f, 0.f, 0.f};   // row-sum accumulators (denominator)
        f32x4 o4B = (f32x4){0.f, 0.f, 0.f, 0.f};

#pragma unroll
        for (int kt = 0; kt < 8; ++kt) {
            const int j0 = 2 * kt, j1 = 2 * kt + 1;

            // ---- UNGUARDED shared loads (always in-bounds) ----
            const short8 kf0a = kf_lds[((j0 * 2 + 0) * 4 + lg) * 16 + lr];
            const short8 kf0b = kf_lds[((j0 * 2 + 1) * 4 + lg) * 16 + lr];
            const short8 kf1a = kf_lds[((j1 * 2 + 0) * 4 + lg) * 16 + lr];
            const short8 kf1b = kf_lds[((j1 * 2 + 1) * 4 + lg) * 16 + lr];
            const short8 vb0 = *(const short8*)&vq_lds[(lg * 64 +  0 + lr) * 16 + (j0 ^ xsw)];
            const short8 vb1 = *(const short8*)&vq_lds[(lg * 64 + 16 + lr) * 16 + (j0 ^ xsw)];
            const short8 vb2 = *(const short8*)&vq_lds[(lg * 64 + 32 + lr) * 16 + (j0 ^ xsw)];
            const short8 vb3 = *(const short8*)&vq_lds[(lg * 64 + 48 + lr) * 16 + (j0 ^ xsw)];

            // ---- strip A tile-pair kt ----
            if (2 * kt < ntA) {
                f32x4 p0 = (f32x4){0.f, 0.f, 0.f, 0.f};
                f32x4 p1 = (f32x4){0.f, 0.f, 0.f, 0.f};
                p0 = MFMA16(kf0a, qfA[0], p0);
                p0 = MFMA16(kf0b, qfA[1], p0);
                const bool h1 = (j1 < ntA);
                if (h1) {
                    p1 = MFMA16(kf1a, qfA[0], p1);
                    p1 = MFMA16(kf1b, qfA[1], p1);
                }
#pragma unroll
                for (int e = 0; e < 4; ++e) p0[e] = __builtin_amdgcn_exp2f(p0[e]);
                if (j0 == sA) {
#pragma unroll
                    for (int e = 0; e < 4; ++e) p0[e] = (4 * lg + e > lr) ? 0.f : p0[e];
                }
                if (h1) {
#pragma unroll
                    for (int e = 0; e < 4; ++e) p1[e] = __builtin_amdgcn_exp2f(p1[e]);
                    if (j1 == sA) {
#pragma unroll
                        for (int e = 0; e < 4; ++e) p1[e] = (4 * lg + e > lr) ? 0.f : p1[e];
                    }
                }
                short8 pa = pack8(p0, p1);
                oA[0] = MFMA16(pa, vb0, oA[0]);
                oA[1] = MFMA16(pa, vb1, oA[1]);
                oA[2] = MFMA16(pa, vb2, oA[2]);
                oA[3] = MFMA16(pa, vb3, oA[3]);
                o4A   = MFMA16(pa, ones, o4A);     // denominator: row-sum of the SAME bf16 P
            }

            // ---- strip B tile-pair kt ----
            if (2 * kt < ntB) {
                f32x4 p0 = (f32x4){0.f, 0.f, 0.f, 0.f};
                f32x4 p1 = (f32x4){0.f, 0.f, 0.f, 0.f};
                p0 = MFMA16(kf0a, qfB[0], p0);
                p0 = MFMA16(kf0b, qfB[1], p0);
                const bool h1 = (j1 < ntB);
                if (h1) {
                    p1 = MFMA16(kf1a, qfB[0], p1);
                    p1 = MFMA16(kf1b, qfB[1], p1);
                }
#pragma unroll
                for (int e = 0; e < 4; ++e) p0[e] = __builtin_amdgcn_exp2f(p0[e]);
                if (j0 == sB) {
#pragma unroll
                    for (int e = 0; e < 4; ++e) p0[e] = (4 * lg + e > lr) ? 0.f : p0[e];
                }
                if (h1) {
#pragma unroll
                    for (int e = 0; e < 4; ++e) p1[e] = __builtin_amdgcn_exp2f(p1[e]);
                    if (j1 == sB) {
#pragma unroll
                        for (int e = 0; e < 4; ++e) p1[e] = (4 * lg + e > lr) ? 0.f : p1[e];
                    }
                }
                short8 pa = pack8(p0, p1);
                oB[0] = MFMA16(pa, vb0, oB[0]);
                oB[1] = MFMA16(pa, vb1, oB[1]);
                oB[2] = MFMA16(pa, vb2, oB[2]);
                oB[3] = MFMA16(pa, vb3, oB[3]);
                o4B   = MFMA16(pa, ones, o4B);
            }
        }

        // ---------- Epilogue: LDS restage (kf/vq dead) -> coalesced dwordx4 stores — proven R4 ----------
        __syncthreads();
#pragma unroll
        for (int sp = 0; sp < 2; ++sp) {
            const int s = sp ? sB : sA;
            const f32x4 o4 = sp ? o4B : o4A;
            float dn[4];
#pragma unroll
            for (int reg = 0; reg < 4; ++reg) dn[reg] = __builtin_amdgcn_rcpf(o4[reg]);
#pragma unroll
            for (int t = 0; t < 4; ++t)
#pragma unroll
                for (int reg = 0; reg < 4; ++reg) {
                    const int row = 4 * lg + reg;                    // query row within strip
                    const int col = (16 * t + lr) ^ (lg << 4);       // XOR key = row>>2 = lg
                    const f32x4 o = sp ? oB[t] : oA[t];
                    stage[(s * 16 + row) * 64 + col] = o[reg] * dn[reg];
                }
        }
        // own-wave data only: compiler inserts the lgkmcnt wait for the ds_write->ds_read dep
#pragma unroll
        for (int sp = 0; sp < 2; ++sp) {
            const int s = sp ? sB : sA;
#pragma unroll
            for (int i = 0; i < 4; ++i) {
                const int row = 4 * i + lg;
                const int col = (4 * lr) ^ (i << 4);                 // XOR key = row>>2 = i
                f32x4 vv = *(const f32x4*)&stage[(s * 16 + row) * 64 + col];
                *(f32x4*)&out[((size_t)b * TB + 16 * s + row) * HH + 4 * lr] = vv;
            }
        }
        // protect stage (aliases kf/vq) from next batch's Phase-B writes
        __syncthreads();
    }
}

extern "C" void kernel_launch(void* const* d_in, const int* in_sizes, int n_in,
                              void* d_out, int out_size, void* d_ws, size_t ws_size,
                              hipStream_t stream) {
    const float* x  = (const float*)d_in[0];
    const float* Wq = (const float*)d_in[1];
    const float* Wk = (const float*)d_in[2];
    const float* Wv = (const float*)d_in[3];
    float* out = (float*)d_out;
    const int Bn = in_sizes[0] / (TB * CC);   // 2048
    if (ws_size >= 3 * 4 * 2 * 64 * sizeof(short8)) {
        short8* wf = (short8*)d_ws;
        pack_w<<<1, 512, 0, stream>>>(Wq, Wk, Wv, wf);
        attn_fused<true><<<Bn / 2, 512, 0, stream>>>(x, Wq, Wk, Wv, wf, out);
    } else {
        attn_fused<false><<<Bn / 2, 512, 0, stream>>>(x, Wq, Wk, Wv, nullptr, out);
    }
}

// Round 18
// 113.631 us; speedup vs baseline: 1.4540x; 1.0010x over previous
//
#include <hip/hip_runtime.h>
#include <hip/hip_bf16.h>

#define TB 256   // T (sequence length)
#define CC 64    // C (embed)
#define HH 64    // H (head size)

typedef __attribute__((ext_vector_type(8))) short short8;   // 8 bf16 (4 VGPRs)
typedef __attribute__((ext_vector_type(4))) float f32x4;    // MFMA C/D frag

#define MFMA16(a, b, c) __builtin_amdgcn_mfma_f32_16x16x32_bf16((a), (b), (c), 0, 0, 0)

// Packed f32->bf16 pair via HIP intrinsic (lowers to v_cvt_pk_bf16_f32) — proven R12.
__device__ __forceinline__ unsigned cvt2(float lo, float hi) {
    union { __hip_bfloat162 h2; unsigned u; } cv;
    cv.h2 = __float22bfloat162_rn(make_float2(lo, hi));
    return cv.u;
}

union S8U { short8 s8; unsigned u32[4]; unsigned long long u64[2]; };

__device__ __forceinline__ short8 pack8(f32x4 a, f32x4 b) {
    S8U r;
    r.u32[0] = cvt2(a[0], a[1]);
    r.u32[1] = cvt2(a[2], a[3]);
    r.u32[2] = cvt2(b[0], b[1]);
    r.u32[3] = cvt2(b[2], b[3]);
    return r.s8;
}

__device__ __forceinline__ unsigned long long pack4(f32x4 a) {
    S8U r;
    r.u32[0] = cvt2(a[0], a[1]);
    r.u32[1] = cvt2(a[2], a[3]);
    return r.u64[0];
}

// Pre-kernel: W -> MFMA-ready bf16 fragments (proven R4). Layout byte-identical to wb frags.
__global__ __launch_bounds__(512, 1)
void pack_w(const float* __restrict__ Wq, const float* __restrict__ Wk,
            const float* __restrict__ Wv, short8* __restrict__ wf) {
    const int tid  = threadIdx.x;
    const int lane = tid & 63;
    const int lr   = lane & 15;
    const int lg   = lane >> 4;
    const int idx  = tid >> 6;        // 0..7
    const int t    = idx >> 1;
    const int kk   = idx & 1;
    const float* Ws[3] = { Wq, Wk, Wv };
#pragma unroll
    for (int m = 0; m < 3; ++m) {
        const f32x4* p4 = (const f32x4*)(Ws[m] + (16 * t + lr) * CC + kk * 32 + lg * 8);
        wf[((m * 4 + t) * 2 + kk) * 64 + lane] = pack8(p4[0], p4[1]);
    }
}

// R14 kernel (proven 65.9us) processing TWO batches per block (grid halved):
// halves ramp/drain tail rounds, amortizes per-block W-frag setup, and lets batch
// n+1's independent global x-loads issue under batch n's Phase C / epilogue.
// Per-batch body is verbatim R14; one extra end-of-batch barrier protects the
// stage <-> kf/vq LDS alias across batches. Block shape pinned at 512/LB(512,4)
// (1024- and 640-thread variants miscompile: R5/R13/R15).
template<bool WSF>
__global__ __launch_bounds__(512, 4)
void attn_fused(const float* __restrict__ x, const float* __restrict__ Wq,
                const float* __restrict__ Wk, const float* __restrict__ Wv,
                const short8* __restrict__ wf, float* __restrict__ out)
{
    // 64 KiB shared, phase-aliased: Phase B/C: kf(32K)+vq(32K); epilogue: fp32 stage[256][64]
    __shared__ __align__(16) char smem[65536];
    short8* kf_lds = (short8*)smem;                                   // [16][2][4][16]
    unsigned long long* vq_lds = (unsigned long long*)(smem + 32768); // [4][64][16]
    float* stage = (float*)smem;

    const int tid  = threadIdx.x;
    const int wave = tid >> 6;
    const int lane = tid & 63;
    const int lr   = lane & 15;
    const int lg   = lane >> 4;
    const int xsw  = (lr & 7) << 1;   // vq swizzle (even -> preserves b128 pairing)

    const int sA = wave;              // light strip (ntA <= 8)
    const int sB = 15 - wave;         // heavy strip (ntB >= 9)
    const int ntA = sA + 1;
    const int ntB = sB + 1;

    const float kexp = 0.125f * 1.44269504088896f;   // scale * log2(e), folded into Q

    // all-ones bf16 B-tile fragment (0x3F80 = bf16 1.0)
    const short8 ones = { (short)0x3F80, (short)0x3F80, (short)0x3F80, (short)0x3F80,
                          (short)0x3F80, (short)0x3F80, (short)0x3F80, (short)0x3F80 };

#pragma unroll
    for (int bb = 0; bb < 2; ++bb) {
        const int b = blockIdx.x * 2 + bb;

        // ---------- Phase A: x fragments for both strips ----------
        short8 xa[2][2];
#pragma unroll
        for (int sp = 0; sp < 2; ++sp) {
            const int s = sp ? sB : sA;
            const float* xr = x + ((size_t)b * TB + s * 16 + lr) * CC;
#pragma unroll
            for (int kk = 0; kk < 2; ++kk) {
                const f32x4* p4 = (const f32x4*)(xr + kk * 32 + lg * 8);
                xa[sp][kk] = pack8(p4[0], p4[1]);
            }
        }

        // ---------- Phase B: q^T,k^T = W@x^T (lane=pos); v = x@W^T (lane=h) — proven R4 ----------
        short8 qfA[2], qfB[2];
        const float* Ws[3] = { Wq, Wk, Wv };
#pragma unroll
        for (int m = 0; m < 3; ++m) {
            short8 wb[4][2];
            if constexpr (WSF) {
#pragma unroll
                for (int t = 0; t < 4; ++t)
#pragma unroll
                    for (int kk = 0; kk < 2; ++kk)
                        wb[t][kk] = wf[((m * 4 + t) * 2 + kk) * 64 + lane];
            } else {
#pragma unroll
                for (int t = 0; t < 4; ++t)
#pragma unroll
                    for (int kk = 0; kk < 2; ++kk) {
                        const f32x4* p4 = (const f32x4*)(Ws[m] + (16 * t + lr) * CC + kk * 32 + lg * 8);
                        wb[t][kk] = pack8(p4[0], p4[1]);
                    }
            }
#pragma unroll
            for (int sp = 0; sp < 2; ++sp) {
                const int s = sp ? sB : sA;
                f32x4 acc[4];
#pragma unroll
                for (int t = 0; t < 4; ++t) acc[t] = (f32x4){0.f, 0.f, 0.f, 0.f};
#pragma unroll
                for (int kk = 0; kk < 2; ++kk)
#pragma unroll
                    for (int t = 0; t < 4; ++t)
                        acc[t] = (m < 2) ? MFMA16(wb[t][kk], xa[sp][kk], acc[t])   // W in A slot -> transposed D
                                         : MFMA16(xa[sp][kk], wb[t][kk], acc[t]);  // x in A slot -> standard D

                if (m == 0) {
                    // fold kexp into Q before bf16 pack (saves a mul per P elem in Phase C)
#pragma unroll
                    for (int t = 0; t < 4; ++t)
#pragma unroll
                        for (int e = 0; e < 4; ++e) acc[t][e] *= kexp;
#pragma unroll
                    for (int kk = 0; kk < 2; ++kk) {
                        short8 q = pack8(acc[2 * kk], acc[2 * kk + 1]);
                        if (sp) qfB[kk] = q; else qfA[kk] = q;
                    }
                } else if (m == 1) {
#pragma unroll
                    for (int kk = 0; kk < 2; ++kk)
                        kf_lds[((s * 2 + kk) * 4 + lg) * 16 + lr] = pack8(acc[2 * kk], acc[2 * kk + 1]);
                } else {
#pragma unroll
                    for (int t = 0; t < 4; ++t)
                        vq_lds[(lg * 64 + 16 * t + lr) * 16 + (s ^ xsw)] = pack4(acc[t]);
                }
            }
        }
        __syncthreads();

        // ---------- Phase C: streaming causal attention; loads hoisted & shared (R11/R12) ----------
        f32x4 oA[4], oB[4];
#pragma unroll
        for (int t = 0; t < 4; ++t) {
            oA[t] = (f32x4){0.f, 0.f, 0.f, 0.f};
            oB[t] = (f32x4){0.f, 0.f, 0.f, 0.f};
        }
        f32x4 o4A = (f32x4){0.f, 0.f, 0.f, 0.f};   // row-sum accumulators (denominator)
        f32x4 o4B = (f32x4){0.f, 0.f, 0.f, 0.f};

#pragma unroll
        for (int kt = 0; kt < 8; ++kt) {
            const int j0 = 2 * kt, j1 = 2 * kt + 1;

            // ---- UNGUARDED shared loads (always in-bounds) ----
            const short8 kf0a = kf_lds[((j0 * 2 + 0) * 4 + lg) * 16 + lr];
            const short8 kf0b = kf_lds[((j0 * 2 + 1) * 4 + lg) * 16 + lr];
            const short8 kf1a = kf_lds[((j1 * 2 + 0) * 4 + lg) * 16 + lr];
            const short8 kf1b = kf_lds[((j1 * 2 + 1) * 4 + lg) * 16 + lr];
            const short8 vb0 = *(const short8*)&vq_lds[(lg * 64 +  0 + lr) * 16 + (j0 ^ xsw)];
            const short8 vb1 = *(const short8*)&vq_lds[(lg * 64 + 16 + lr) * 16 + (j0 ^ xsw)];
            const short8 vb2 = *(const short8*)&vq_lds[(lg * 64 + 32 + lr) * 16 + (j0 ^ xsw)];
            const short8 vb3 = *(const short8*)&vq_lds[(lg * 64 + 48 + lr) * 16 + (j0 ^ xsw)];

            // ---- strip A tile-pair kt ----
            if (2 * kt < ntA) {
                f32x4 p0 = (f32x4){0.f, 0.f, 0.f, 0.f};
                f32x4 p1 = (f32x4){0.f, 0.f, 0.f, 0.f};
                p0 = MFMA16(kf0a, qfA[0], p0);
                p0 = MFMA16(kf0b, qfA[1], p0);
                const bool h1 = (j1 < ntA);
                if (h1) {
                    p1 = MFMA16(kf1a, qfA[0], p1);
                    p1 = MFMA16(kf1b, qfA[1], p1);
                }
#pragma unroll
                for (int e = 0; e < 4; ++e) p0[e] = __builtin_amdgcn_exp2f(p0[e]);
                if (j0 == sA) {
#pragma unroll
                    for (int e = 0; e < 4; ++e) p0[e] = (4 * lg + e > lr) ? 0.f : p0[e];
                }
                if (h1) {
#pragma unroll
                    for (int e = 0; e < 4; ++e) p1[e] = __builtin_amdgcn_exp2f(p1[e]);
                    if (j1 == sA) {
#pragma unroll
                        for (int e = 0; e < 4; ++e) p1[e] = (4 * lg + e > lr) ? 0.f : p1[e];
                    }
                }
                short8 pa = pack8(p0, p1);
                oA[0] = MFMA16(pa, vb0, oA[0]);
                oA[1] = MFMA16(pa, vb1, oA[1]);
                oA[2] = MFMA16(pa, vb2, oA[2]);
                oA[3] = MFMA16(pa, vb3, oA[3]);
                o4A   = MFMA16(pa, ones, o4A);     // denominator: row-sum of the SAME bf16 P
            }

            // ---- strip B tile-pair kt ----
            if (2 * kt < ntB) {
                f32x4 p0 = (f32x4){0.f, 0.f, 0.f, 0.f};
                f32x4 p1 = (f32x4){0.f, 0.f, 0.f, 0.f};
                p0 = MFMA16(kf0a, qfB[0], p0);
                p0 = MFMA16(kf0b, qfB[1], p0);
                const bool h1 = (j1 < ntB);
                if (h1) {
                    p1 = MFMA16(kf1a, qfB[0], p1);
                    p1 = MFMA16(kf1b, qfB[1], p1);
                }
#pragma unroll
                for (int e = 0; e < 4; ++e) p0[e] = __builtin_amdgcn_exp2f(p0[e]);
                if (j0 == sB) {
#pragma unroll
                    for (int e = 0; e < 4; ++e) p0[e] = (4 * lg + e > lr) ? 0.f : p0[e];
                }
                if (h1) {
#pragma unroll
                    for (int e = 0; e < 4; ++e) p1[e] = __builtin_amdgcn_exp2f(p1[e]);
                    if (j1 == sB) {
#pragma unroll
                        for (int e = 0; e < 4; ++e) p1[e] = (4 * lg + e > lr) ? 0.f : p1[e];
                    }
                }
                short8 pa = pack8(p0, p1);
                oB[0] = MFMA16(pa, vb0, oB[0]);
                oB[1] = MFMA16(pa, vb1, oB[1]);
                oB[2] = MFMA16(pa, vb2, oB[2]);
                oB[3] = MFMA16(pa, vb3, oB[3]);
                o4B   = MFMA16(pa, ones, o4B);
            }
        }

        // ---------- Epilogue: LDS restage (kf/vq dead) -> coalesced dwordx4 stores — proven R4 ----------
        __syncthreads();
#pragma unroll
        for (int sp = 0; sp < 2; ++sp) {
            const int s = sp ? sB : sA;
            const f32x4 o4 = sp ? o4B : o4A;
            float dn[4];
#pragma unroll
            for (int reg = 0; reg < 4; ++reg) dn[reg] = __builtin_amdgcn_rcpf(o4[reg]);
#pragma unroll
            for (int t = 0; t < 4; ++t)
#pragma unroll
                for (int reg = 0; reg < 4; ++reg) {
                    const int row = 4 * lg + reg;                    // query row within strip
                    const int col = (16 * t + lr) ^ (lg << 4);       // XOR key = row>>2 = lg
                    const f32x4 o = sp ? oB[t] : oA[t];
                    stage[(s * 16 + row) * 64 + col] = o[reg] * dn[reg];
                }
        }
        // own-wave data only: compiler inserts the lgkmcnt wait for the ds_write->ds_read dep
#pragma unroll
        for (int sp = 0; sp < 2; ++sp) {
            const int s = sp ? sB : sA;
#pragma unroll
            for (int i = 0; i < 4; ++i) {
                const int row = 4 * i + lg;
                const int col = (4 * lr) ^ (i << 4);                 // XOR key = row>>2 = i
                f32x4 vv = *(const f32x4*)&stage[(s * 16 + row) * 64 + col];
                *(f32x4*)&out[((size_t)b * TB + 16 * s + row) * HH + 4 * lr] = vv;
            }
        }
        // protect stage (aliases kf/vq) from next batch's Phase-B writes
        __syncthreads();
    }
}

extern "C" void kernel_launch(void* const* d_in, const int* in_sizes, int n_in,
                              void* d_out, int out_size, void* d_ws, size_t ws_size,
                              hipStream_t stream) {
    const float* x  = (const float*)d_in[0];
    const float* Wq = (const float*)d_in[1];
    const float* Wk = (const float*)d_in[2];
    const float* Wv = (const float*)d_in[3];
    float* out = (float*)d_out;
    const int Bn = in_sizes[0] / (TB * CC);   // 2048
    if (ws_size >= 3 * 4 * 2 * 64 * sizeof(short8)) {
        short8* wf = (short8*)d_ws;
        pack_w<<<1, 512, 0, stream>>>(Wq, Wk, Wv, wf);
        attn_fused<true><<<Bn / 2, 512, 0, stream>>>(x, Wq, Wk, Wv, wf, out);
    } else {
        attn_fused<false><<<Bn / 2, 512, 0, stream>>>(x, Wq, Wk, Wv, nullptr, out);
    }
}

// Round 19
// 69.531 us; speedup vs baseline: 2.3762x; 1.6342x over previous
//
#include <hip/hip_runtime.h>
#include <hip/hip_bf16.h>

#define TB 256   // T (sequence length)
#define CC 64    // C (embed)
#define HH 64    // H (head size)

typedef __attribute__((ext_vector_type(8))) short short8;   // 8 bf16 (4 VGPRs)
typedef __attribute__((ext_vector_type(4))) float f32x4;    // MFMA C/D frag

#define MFMA16(a, b, c) __builtin_amdgcn_mfma_f32_16x16x32_bf16((a), (b), (c), 0, 0, 0)

// Packed f32->bf16 pair via HIP intrinsic (lowers to v_cvt_pk_bf16_f32) — proven R12.
__device__ __forceinline__ unsigned cvt2(float lo, float hi) {
    union { __hip_bfloat162 h2; unsigned u; } cv;
    cv.h2 = __float22bfloat162_rn(make_float2(lo, hi));
    return cv.u;
}

union S8U { short8 s8; unsigned u32[4]; unsigned long long u64[2]; };

__device__ __forceinline__ short8 pack8(f32x4 a, f32x4 b) {
    S8U r;
    r.u32[0] = cvt2(a[0], a[1]);
    r.u32[1] = cvt2(a[2], a[3]);
    r.u32[2] = cvt2(b[0], b[1]);
    r.u32[3] = cvt2(b[2], b[3]);
    return r.s8;
}

__device__ __forceinline__ unsigned long long pack4(f32x4 a) {
    S8U r;
    r.u32[0] = cvt2(a[0], a[1]);
    r.u32[1] = cvt2(a[2], a[3]);
    return r.u64[0];
}

// Pre-kernel: W -> MFMA-ready bf16 fragments (proven R4). Layout byte-identical to wb frags.
__global__ __launch_bounds__(512, 1)
void pack_w(const float* __restrict__ Wq, const float* __restrict__ Wk,
            const float* __restrict__ Wv, short8* __restrict__ wf) {
    const int tid  = threadIdx.x;
    const int lane = tid & 63;
    const int lr   = lane & 15;
    const int lg   = lane >> 4;
    const int idx  = tid >> 6;        // 0..7
    const int t    = idx >> 1;
    const int kk   = idx & 1;
    const float* Ws[3] = { Wq, Wk, Wv };
#pragma unroll
    for (int m = 0; m < 3; ++m) {
        const f32x4* p4 = (const f32x4*)(Ws[m] + (16 * t + lr) * CC + kk * 32 + lg * 8);
        wf[((m * 4 + t) * 2 + kk) * 64 + lane] = pack8(p4[0], p4[1]);
    }
}

// R14 shell (proven 65.9us, single batch/block, grid 2048) with TRANSPOSED PV:
//   O^T = MFMA16(A=vb, B=pa)  ->  lane lr owns query row 16s+lr; reg-quad = 4
//   consecutive h at 16t+4lg. Direct f32x4 global stores — the LDS restage, its
//   barrier, and all epilogue shuffles are DELETED (one barrier total).
//   Denominator: o4 = MFMA16(ones, pa, o4) replicates denom[query=lr] in every
//   reg -> single rcp per strip. Same fragments as R14, operands swapped only.
template<bool WSF>
__global__ __launch_bounds__(512, 4)
void attn_fused(const float* __restrict__ x, const float* __restrict__ Wq,
                const float* __restrict__ Wk, const float* __restrict__ Wv,
                const short8* __restrict__ wf, float* __restrict__ out)
{
    // 64 KiB shared: kf(32K)+vq(32K). No epilogue stage (direct stores).
    __shared__ __align__(16) char smem[65536];
    short8* kf_lds = (short8*)smem;                                   // [16][2][4][16]
    unsigned long long* vq_lds = (unsigned long long*)(smem + 32768); // [4][64][16]

    const int b    = blockIdx.x;
    const int tid  = threadIdx.x;
    const int wave = tid >> 6;
    const int lane = tid & 63;
    const int lr   = lane & 15;
    const int lg   = lane >> 4;
    const int xsw  = (lr & 7) << 1;   // vq swizzle (even -> preserves b128 pairing)

    const int sA = wave;              // light strip (ntA <= 8)
    const int sB = 15 - wave;         // heavy strip (ntB >= 9)
    const int ntA = sA + 1;
    const int ntB = sB + 1;

    const float kexp = 0.125f * 1.44269504088896f;   // scale * log2(e), folded into Q

    // all-ones bf16 fragment (0x3F80 = bf16 1.0) — A-operand of the denom MFMA
    const short8 ones = { (short)0x3F80, (short)0x3F80, (short)0x3F80, (short)0x3F80,
                          (short)0x3F80, (short)0x3F80, (short)0x3F80, (short)0x3F80 };

    // ---------- Phase A: x fragments for both strips ----------
    short8 xa[2][2];
#pragma unroll
    for (int sp = 0; sp < 2; ++sp) {
        const int s = sp ? sB : sA;
        const float* xr = x + ((size_t)b * TB + s * 16 + lr) * CC;
#pragma unroll
        for (int kk = 0; kk < 2; ++kk) {
            const f32x4* p4 = (const f32x4*)(xr + kk * 32 + lg * 8);
            xa[sp][kk] = pack8(p4[0], p4[1]);
        }
    }

    // ---------- Phase B: q^T,k^T = W@x^T (lane=pos); v = x@W^T (lane=h) — proven R4 ----------
    short8 qfA[2], qfB[2];
    const float* Ws[3] = { Wq, Wk, Wv };
#pragma unroll
    for (int m = 0; m < 3; ++m) {
        short8 wb[4][2];
        if constexpr (WSF) {
#pragma unroll
            for (int t = 0; t < 4; ++t)
#pragma unroll
                for (int kk = 0; kk < 2; ++kk)
                    wb[t][kk] = wf[((m * 4 + t) * 2 + kk) * 64 + lane];
        } else {
#pragma unroll
            for (int t = 0; t < 4; ++t)
#pragma unroll
                for (int kk = 0; kk < 2; ++kk) {
                    const f32x4* p4 = (const f32x4*)(Ws[m] + (16 * t + lr) * CC + kk * 32 + lg * 8);
                    wb[t][kk] = pack8(p4[0], p4[1]);
                }
        }
#pragma unroll
        for (int sp = 0; sp < 2; ++sp) {
            const int s = sp ? sB : sA;
            f32x4 acc[4];
#pragma unroll
            for (int t = 0; t < 4; ++t) acc[t] = (f32x4){0.f, 0.f, 0.f, 0.f};
#pragma unroll
            for (int kk = 0; kk < 2; ++kk)
#pragma unroll
                for (int t = 0; t < 4; ++t)
                    acc[t] = (m < 2) ? MFMA16(wb[t][kk], xa[sp][kk], acc[t])   // W in A slot -> transposed D
                                     : MFMA16(xa[sp][kk], wb[t][kk], acc[t]);  // x in A slot -> standard D

            if (m == 0) {
                // fold kexp into Q before bf16 pack (saves a mul per P elem in Phase C)
#pragma unroll
                for (int t = 0; t < 4; ++t)
#pragma unroll
                    for (int e = 0; e < 4; ++e) acc[t][e] *= kexp;
#pragma unroll
                for (int kk = 0; kk < 2; ++kk) {
                    short8 q = pack8(acc[2 * kk], acc[2 * kk + 1]);
                    if (sp) qfB[kk] = q; else qfA[kk] = q;
                }
            } else if (m == 1) {
#pragma unroll
                for (int kk = 0; kk < 2; ++kk)
                    kf_lds[((s * 2 + kk) * 4 + lg) * 16 + lr] = pack8(acc[2 * kk], acc[2 * kk + 1]);
            } else {
#pragma unroll
                for (int t = 0; t < 4; ++t)
                    vq_lds[(lg * 64 + 16 * t + lr) * 16 + (s ^ xsw)] = pack4(acc[t]);
            }
        }
    }
    __syncthreads();   // the kernel's ONLY barrier

    // ---------- Phase C: streaming causal attention; O^T accumulation ----------
    f32x4 oA[4], oB[4];
#pragma unroll
    for (int t = 0; t < 4; ++t) {
        oA[t] = (f32x4){0.f, 0.f, 0.f, 0.f};
        oB[t] = (f32x4){0.f, 0.f, 0.f, 0.f};
    }
    f32x4 o4A = (f32x4){0.f, 0.f, 0.f, 0.f};   // denom[query=lr] replicated per reg
    f32x4 o4B = (f32x4){0.f, 0.f, 0.f, 0.f};

#pragma unroll
    for (int kt = 0; kt < 8; ++kt) {
        const int j0 = 2 * kt, j1 = 2 * kt + 1;

        // ---- UNGUARDED shared loads (always in-bounds) ----
        const short8 kf0a = kf_lds[((j0 * 2 + 0) * 4 + lg) * 16 + lr];
        const short8 kf0b = kf_lds[((j0 * 2 + 1) * 4 + lg) * 16 + lr];
        const short8 kf1a = kf_lds[((j1 * 2 + 0) * 4 + lg) * 16 + lr];
        const short8 kf1b = kf_lds[((j1 * 2 + 1) * 4 + lg) * 16 + lr];
        const short8 vb0 = *(const short8*)&vq_lds[(lg * 64 +  0 + lr) * 16 + (j0 ^ xsw)];
        const short8 vb1 = *(const short8*)&vq_lds[(lg * 64 + 16 + lr) * 16 + (j0 ^ xsw)];
        const short8 vb2 = *(const short8*)&vq_lds[(lg * 64 + 32 + lr) * 16 + (j0 ^ xsw)];
        const short8 vb3 = *(const short8*)&vq_lds[(lg * 64 + 48 + lr) * 16 + (j0 ^ xsw)];

        // ---- strip A tile-pair kt ----
        if (2 * kt < ntA) {
            f32x4 p0 = (f32x4){0.f, 0.f, 0.f, 0.f};
            f32x4 p1 = (f32x4){0.f, 0.f, 0.f, 0.f};
            p0 = MFMA16(kf0a, qfA[0], p0);
            p0 = MFMA16(kf0b, qfA[1], p0);
            const bool h1 = (j1 < ntA);
            if (h1) {
                p1 = MFMA16(kf1a, qfA[0], p1);
                p1 = MFMA16(kf1b, qfA[1], p1);
            }
#pragma unroll
            for (int e = 0; e < 4; ++e) p0[e] = __builtin_amdgcn_exp2f(p0[e]);
            if (j0 == sA) {
#pragma unroll
                for (int e = 0; e < 4; ++e) p0[e] = (4 * lg + e > lr) ? 0.f : p0[e];
            }
            if (h1) {
#pragma unroll
                for (int e = 0; e < 4; ++e) p1[e] = __builtin_amdgcn_exp2f(p1[e]);
                if (j1 == sA) {
#pragma unroll
                    for (int e = 0; e < 4; ++e) p1[e] = (4 * lg + e > lr) ? 0.f : p1[e];
                }
            }
            short8 pa = pack8(p0, p1);
            // O^T: operands swapped (A=V^T frag, B=P frag) -> lane owns query row lr
            oA[0] = MFMA16(vb0, pa, oA[0]);
            oA[1] = MFMA16(vb1, pa, oA[1]);
            oA[2] = MFMA16(vb2, pa, oA[2]);
            oA[3] = MFMA16(vb3, pa, oA[3]);
            o4A   = MFMA16(ones, pa, o4A);     // denom[query=lr], replicated
        }

        // ---- strip B tile-pair kt ----
        if (2 * kt < ntB) {
            f32x4 p0 = (f32x4){0.f, 0.f, 0.f, 0.f};
            f32x4 p1 = (f32x4){0.f, 0.f, 0.f, 0.f};
            p0 = MFMA16(kf0a, qfB[0], p0);
            p0 = MFMA16(kf0b, qfB[1], p0);
            const bool h1 = (j1 < ntB);
            if (h1) {
                p1 = MFMA16(kf1a, qfB[0], p1);
                p1 = MFMA16(kf1b, qfB[1], p1);
            }
#pragma unroll
            for (int e = 0; e < 4; ++e) p0[e] = __builtin_amdgcn_exp2f(p0[e]);
            if (j0 == sB) {
#pragma unroll
                for (int e = 0; e < 4; ++e) p0[e] = (4 * lg + e > lr) ? 0.f : p0[e];
            }
            if (h1) {
#pragma unroll
                for (int e = 0; e < 4; ++e) p1[e] = __builtin_amdgcn_exp2f(p1[e]);
                if (j1 == sB) {
#pragma unroll
                    for (int e = 0; e < 4; ++e) p1[e] = (4 * lg + e > lr) ? 0.f : p1[e];
                }
            }
            short8 pa = pack8(p0, p1);
            oB[0] = MFMA16(vb0, pa, oB[0]);
            oB[1] = MFMA16(vb1, pa, oB[1]);
            oB[2] = MFMA16(vb2, pa, oB[2]);
            oB[3] = MFMA16(vb3, pa, oB[3]);
            o4B   = MFMA16(ones, pa, o4B);
        }
    }

    // ---------- Epilogue: direct f32x4 stores (no LDS, no barrier, no shuffles) ----------
    // lane lr owns query row 16s+lr; oX[t][reg] = O[row][16t + 4lg + reg]
#pragma unroll
    for (int sp = 0; sp < 2; ++sp) {
        const int s = sp ? sB : sA;
        const float dn = __builtin_amdgcn_rcpf(sp ? o4B[0] : o4A[0]);
        float* orow = out + ((size_t)b * TB + 16 * s + lr) * HH + 4 * lg;
#pragma unroll
        for (int t = 0; t < 4; ++t) {
            const f32x4 o = sp ? oB[t] : oA[t];
            f32x4 vv;
            vv[0] = o[0] * dn; vv[1] = o[1] * dn;
            vv[2] = o[2] * dn; vv[3] = o[3] * dn;
            *(f32x4*)&orow[16 * t] = vv;
        }
    }
}

extern "C" void kernel_launch(void* const* d_in, const int* in_sizes, int n_in,
                              void* d_out, int out_size, void* d_ws, size_t ws_size,
                              hipStream_t stream) {
    const float* x  = (const float*)d_in[0];
    const float* Wq = (const float*)d_in[1];
    const float* Wk = (const float*)d_in[2];
    const float* Wv = (const float*)d_in[3];
    float* out = (float*)d_out;
    const int Bn = in_sizes[0] / (TB * CC);   // 2048
    if (ws_size >= 3 * 4 * 2 * 64 * sizeof(short8)) {
        short8* wf = (short8*)d_ws;
        pack_w<<<1, 512, 0, stream>>>(Wq, Wk, Wv, wf);
        attn_fused<true><<<Bn, 512, 0, stream>>>(x, Wq, Wk, Wv, wf, out);
    } else {
        attn_fused<false><<<Bn, 512, 0, stream>>>(x, Wq, Wk, Wv, nullptr, out);
    }
}

// Round 21
// 65.927 us; speedup vs baseline: 2.5061x; 1.0547x over previous
//
#include <hip/hip_runtime.h>
#include <hip/hip_bf16.h>

#define TB 256   // T (sequence length)
#define CC 64    // C (embed)
#define HH 64    // H (head size)

typedef __attribute__((ext_vector_type(8))) short short8;   // 8 bf16 (4 VGPRs)
typedef __attribute__((ext_vector_type(4))) float f32x4;    // MFMA C/D frag

#define MFMA16(a, b, c) __builtin_amdgcn_mfma_f32_16x16x32_bf16((a), (b), (c), 0, 0, 0)

// Packed f32->bf16 pair via HIP intrinsic (lowers to v_cvt_pk_bf16_f32) — proven R12.
__device__ __forceinline__ unsigned cvt2(float lo, float hi) {
    union { __hip_bfloat162 h2; unsigned u; } cv;
    cv.h2 = __float22bfloat162_rn(make_float2(lo, hi));
    return cv.u;
}

union S8U { short8 s8; unsigned u32[4]; unsigned long long u64[2]; };

__device__ __forceinline__ short8 pack8(f32x4 a, f32x4 b) {
    S8U r;
    r.u32[0] = cvt2(a[0], a[1]);
    r.u32[1] = cvt2(a[2], a[3]);
    r.u32[2] = cvt2(b[0], b[1]);
    r.u32[3] = cvt2(b[2], b[3]);
    return r.s8;
}

__device__ __forceinline__ unsigned long long pack4(f32x4 a) {
    S8U r;
    r.u32[0] = cvt2(a[0], a[1]);
    r.u32[1] = cvt2(a[2], a[3]);
    return r.u64[0];
}

// Pre-kernel: W -> MFMA-ready bf16 fragments (proven R4). Layout byte-identical to wb frags.
__global__ __launch_bounds__(512, 1)
void pack_w(const float* __restrict__ Wq, const float* __restrict__ Wk,
            const float* __restrict__ Wv, short8* __restrict__ wf) {
    const int tid  = threadIdx.x;
    const int lane = tid & 63;
    const int lr   = lane & 15;
    const int lg   = lane >> 4;
    const int idx  = tid >> 6;        // 0..7
    const int t    = idx >> 1;
    const int kk   = idx & 1;
    const float* Ws[3] = { Wq, Wk, Wv };
#pragma unroll
    for (int m = 0; m < 3; ++m) {
        const f32x4* p4 = (const f32x4*)(Ws[m] + (16 * t + lr) * CC + kk * 32 + lg * 8);
        wf[((m * 4 + t) * 2 + kk) * 64 + lane] = pack8(p4[0], p4[1]);
    }
}

// R19 body (O^T PV, proven) + R14-style staged coalesced epilogue, upgraded to
// b128 stage writes: O^T layout gives each lane 4 CONSECUTIVE cols per reg-quad
// -> 4x ds_write_b128 per strip (vs R14's 16x b32), zero denominator shuffles
// (o4[0] already = denom[row=lr]), quad-swizzle q^=(row&7) for bank spread.
template<bool WSF>
__global__ __launch_bounds__(512, 4)
void attn_fused(const float* __restrict__ x, const float* __restrict__ Wq,
                const float* __restrict__ Wk, const float* __restrict__ Wv,
                const short8* __restrict__ wf, float* __restrict__ out)
{
    // 64 KiB shared, phase-aliased: Phase B/C: kf(32K)+vq(32K); epilogue: fp32 stage[256][64]
    __shared__ __align__(16) char smem[65536];
    short8* kf_lds = (short8*)smem;                                   // [16][2][4][16]
    unsigned long long* vq_lds = (unsigned long long*)(smem + 32768); // [4][64][16]
    float* stage = (float*)smem;

    const int b    = blockIdx.x;
    const int tid  = threadIdx.x;
    const int wave = tid >> 6;
    const int lane = tid & 63;
    const int lr   = lane & 15;
    const int lg   = lane >> 4;
    const int xsw  = (lr & 7) << 1;   // vq swizzle (even -> preserves b128 pairing)

    const int sA = wave;              // light strip (ntA <= 8)
    const int sB = 15 - wave;         // heavy strip (ntB >= 9)
    const int ntA = sA + 1;
    const int ntB = sB + 1;

    const float kexp = 0.125f * 1.44269504088896f;   // scale * log2(e), folded into Q

    // all-ones bf16 fragment (0x3F80 = bf16 1.0) — A-operand of the denom MFMA
    const short8 ones = { (short)0x3F80, (short)0x3F80, (short)0x3F80, (short)0x3F80,
                          (short)0x3F80, (short)0x3F80, (short)0x3F80, (short)0x3F80 };

    // ---------- Phase A: x fragments for both strips ----------
    short8 xa[2][2];
#pragma unroll
    for (int sp = 0; sp < 2; ++sp) {
        const int s = sp ? sB : sA;
        const float* xr = x + ((size_t)b * TB + s * 16 + lr) * CC;
#pragma unroll
        for (int kk = 0; kk < 2; ++kk) {
            const f32x4* p4 = (const f32x4*)(xr + kk * 32 + lg * 8);
            xa[sp][kk] = pack8(p4[0], p4[1]);
        }
    }

    // ---------- Phase B: q^T,k^T = W@x^T (lane=pos); v = x@W^T (lane=h) — proven R4 ----------
    short8 qfA[2], qfB[2];
    const float* Ws[3] = { Wq, Wk, Wv };
#pragma unroll
    for (int m = 0; m < 3; ++m) {
        short8 wb[4][2];
        if constexpr (WSF) {
#pragma unroll
            for (int t = 0; t < 4; ++t)
#pragma unroll
                for (int kk = 0; kk < 2; ++kk)
                    wb[t][kk] = wf[((m * 4 + t) * 2 + kk) * 64 + lane];
        } else {
#pragma unroll
            for (int t = 0; t < 4; ++t)
#pragma unroll
                for (int kk = 0; kk < 2; ++kk) {
                    const f32x4* p4 = (const f32x4*)(Ws[m] + (16 * t + lr) * CC + kk * 32 + lg * 8);
                    wb[t][kk] = pack8(p4[0], p4[1]);
                }
        }
#pragma unroll
        for (int sp = 0; sp < 2; ++sp) {
            const int s = sp ? sB : sA;
            f32x4 acc[4];
#pragma unroll
            for (int t = 0; t < 4; ++t) acc[t] = (f32x4){0.f, 0.f, 0.f, 0.f};
#pragma unroll
            for (int kk = 0; kk < 2; ++kk)
#pragma unroll
                for (int t = 0; t < 4; ++t)
                    acc[t] = (m < 2) ? MFMA16(wb[t][kk], xa[sp][kk], acc[t])   // W in A slot -> transposed D
                                     : MFMA16(xa[sp][kk], wb[t][kk], acc[t]);  // x in A slot -> standard D

            if (m == 0) {
                // fold kexp into Q before bf16 pack (saves a mul per P elem in Phase C)
#pragma unroll
                for (int t = 0; t < 4; ++t)
#pragma unroll
                    for (int e = 0; e < 4; ++e) acc[t][e] *= kexp;
#pragma unroll
                for (int kk = 0; kk < 2; ++kk) {
                    short8 q = pack8(acc[2 * kk], acc[2 * kk + 1]);
                    if (sp) qfB[kk] = q; else qfA[kk] = q;
                }
            } else if (m == 1) {
#pragma unroll
                for (int kk = 0; kk < 2; ++kk)
                    kf_lds[((s * 2 + kk) * 4 + lg) * 16 + lr] = pack8(acc[2 * kk], acc[2 * kk + 1]);
            } else {
#pragma unroll
                for (int t = 0; t < 4; ++t)
                    vq_lds[(lg * 64 + 16 * t + lr) * 16 + (s ^ xsw)] = pack4(acc[t]);
            }
        }
    }
    __syncthreads();

    // ---------- Phase C: streaming causal attention; O^T accumulation (R19-proven) ----------
    f32x4 oA[4], oB[4];
#pragma unroll
    for (int t = 0; t < 4; ++t) {
        oA[t] = (f32x4){0.f, 0.f, 0.f, 0.f};
        oB[t] = (f32x4){0.f, 0.f, 0.f, 0.f};
    }
    f32x4 o4A = (f32x4){0.f, 0.f, 0.f, 0.f};   // denom[query=lr] replicated per reg
    f32x4 o4B = (f32x4){0.f, 0.f, 0.f, 0.f};

#pragma unroll
    for (int kt = 0; kt < 8; ++kt) {
        const int j0 = 2 * kt, j1 = 2 * kt + 1;

        // ---- UNGUARDED shared loads (always in-bounds) ----
        const short8 kf0a = kf_lds[((j0 * 2 + 0) * 4 + lg) * 16 + lr];
        const short8 kf0b = kf_lds[((j0 * 2 + 1) * 4 + lg) * 16 + lr];
        const short8 kf1a = kf_lds[((j1 * 2 + 0) * 4 + lg) * 16 + lr];
        const short8 kf1b = kf_lds[((j1 * 2 + 1) * 4 + lg) * 16 + lr];
        const short8 vb0 = *(const short8*)&vq_lds[(lg * 64 +  0 + lr) * 16 + (j0 ^ xsw)];
        const short8 vb1 = *(const short8*)&vq_lds[(lg * 64 + 16 + lr) * 16 + (j0 ^ xsw)];
        const short8 vb2 = *(const short8*)&vq_lds[(lg * 64 + 32 + lr) * 16 + (j0 ^ xsw)];
        const short8 vb3 = *(const short8*)&vq_lds[(lg * 64 + 48 + lr) * 16 + (j0 ^ xsw)];

        // ---- strip A tile-pair kt ----
        if (2 * kt < ntA) {
            f32x4 p0 = (f32x4){0.f, 0.f, 0.f, 0.f};
            f32x4 p1 = (f32x4){0.f, 0.f, 0.f, 0.f};
            p0 = MFMA16(kf0a, qfA[0], p0);
            p0 = MFMA16(kf0b, qfA[1], p0);
            const bool h1 = (j1 < ntA);
            if (h1) {
                p1 = MFMA16(kf1a, qfA[0], p1);
                p1 = MFMA16(kf1b, qfA[1], p1);
            }
#pragma unroll
            for (int e = 0; e < 4; ++e) p0[e] = __builtin_amdgcn_exp2f(p0[e]);
            if (j0 == sA) {
#pragma unroll
                for (int e = 0; e < 4; ++e) p0[e] = (4 * lg + e > lr) ? 0.f : p0[e];
            }
            if (h1) {
#pragma unroll
                for (int e = 0; e < 4; ++e) p1[e] = __builtin_amdgcn_exp2f(p1[e]);
                if (j1 == sA) {
#pragma unroll
                    for (int e = 0; e < 4; ++e) p1[e] = (4 * lg + e > lr) ? 0.f : p1[e];
                }
            }
            short8 pa = pack8(p0, p1);
            oA[0] = MFMA16(vb0, pa, oA[0]);
            oA[1] = MFMA16(vb1, pa, oA[1]);
            oA[2] = MFMA16(vb2, pa, oA[2]);
            oA[3] = MFMA16(vb3, pa, oA[3]);
            o4A   = MFMA16(ones, pa, o4A);     // denom[query=lr], replicated
        }

        // ---- strip B tile-pair kt ----
        if (2 * kt < ntB) {
            f32x4 p0 = (f32x4){0.f, 0.f, 0.f, 0.f};
            f32x4 p1 = (f32x4){0.f, 0.f, 0.f, 0.f};
            p0 = MFMA16(kf0a, qfB[0], p0);
            p0 = MFMA16(kf0b, qfB[1], p0);
            const bool h1 = (j1 < ntB);
            if (h1) {
                p1 = MFMA16(kf1a, qfB[0], p1);
                p1 = MFMA16(kf1b, qfB[1], p1);
            }
#pragma unroll
            for (int e = 0; e < 4; ++e) p0[e] = __builtin_amdgcn_exp2f(p0[e]);
            if (j0 == sB) {
#pragma unroll
                for (int e = 0; e < 4; ++e) p0[e] = (4 * lg + e > lr) ? 0.f : p0[e];
            }
            if (h1) {
#pragma unroll
                for (int e = 0; e < 4; ++e) p1[e] = __builtin_amdgcn_exp2f(p1[e]);
                if (j1 == sB) {
#pragma unroll
                    for (int e = 0; e < 4; ++e) p1[e] = (4 * lg + e > lr) ? 0.f : p1[e];
                }
            }
            short8 pa = pack8(p0, p1);
            oB[0] = MFMA16(vb0, pa, oB[0]);
            oB[1] = MFMA16(vb1, pa, oB[1]);
            oB[2] = MFMA16(vb2, pa, oB[2]);
            oB[3] = MFMA16(vb3, pa, oB[3]);
            o4B   = MFMA16(ones, pa, o4B);
        }
    }

    // ---------- Epilogue: b128 LDS restage (O^T layout) -> coalesced dwordx4 stores ----------
    __syncthreads();   // kf/vq reads complete before stage overwrite
#pragma unroll
    for (int sp = 0; sp < 2; ++sp) {
        const int s = sp ? sB : sA;
        const float dn = __builtin_amdgcn_rcpf(sp ? o4B[0] : o4A[0]);  // lane lr = row lr's denom
#pragma unroll
        for (int t = 0; t < 4; ++t) {
            const f32x4 o = sp ? oB[t] : oA[t];
            f32x4 vv;
            vv[0] = o[0] * dn; vv[1] = o[1] * dn;
            vv[2] = o[2] * dn; vv[3] = o[3] * dn;
            const int q = (4 * t + lg) ^ (lr & 7);        // quad-swizzle, key = row&7
            *(f32x4*)&stage[(s * 16 + lr) * 64 + 4 * q] = vv;
        }
    }
    // own-wave data only: compiler inserts the lgkmcnt wait for the ds_write->ds_read dep
#pragma unroll
    for (int sp = 0; sp < 2; ++sp) {
        const int s = sp ? sB : sA;
#pragma unroll
        for (int i = 0; i < 4; ++i) {
            const int row = 4 * i + lg;
            const int q = lr ^ (row & 7);                 // same key as write (row&7)
            f32x4 vv = *(const f32x4*)&stage[(s * 16 + row) * 64 + 4 * q];
            *(f32x4*)&out[((size_t)b * TB + 16 * s + row) * HH + 4 * lr] = vv;
        }
    }
}

extern "C" void kernel_launch(void* const* d_in, const int* in_sizes, int n_in,
                              void* d_out, int out_size, void* d_ws, size_t ws_size,
                              hipStream_t stream) {
    const float* x  = (const float*)d_in[0];
    const float* Wq = (const float*)d_in[1];
    const float* Wk = (const float*)d_in[2];
    const float* Wv = (const float*)d_in[3];
    float* out = (float*)d_out;
    const int Bn = in_sizes[0] / (TB * CC);   // 2048
    if (ws_size >= 3 * 4 * 2 * 64 * sizeof(short8)) {
        short8* wf = (short8*)d_ws;
        pack_w<<<1, 512, 0, stream>>>(Wq, Wk, Wv, wf);
        attn_fused<true><<<Bn, 512, 0, stream>>>(x, Wq, Wk, Wv, wf, out);
    } else {
        attn_fused<false><<<Bn, 512, 0, stream>>>(x, Wq, Wk, Wv, nullptr, out);
    }
}